// Round 7
// baseline (349.260 us; speedup 1.0000x reference)
//
#include <hip/hip_runtime.h>

// KMeans soft-assignment via bf16 hi/lo split MFMA (3 passes), fused softmax.
// logits = (2*x.c - ||c||^2)/T, T=0.1; ||x||^2 cancels in softmax.
// R7: LDS staging via VGPR round-trip (batched coalesced loads -> ds_write),
// NO global_load_lds (R3: phantom WRITE), NO nontemporal stores (R4: TCC churn).
// x: [32768,256] f32, c: [512,256] f32, out: [32768,512] f32
#define NROWS 32768
#define KC 512
#define DDIM 256
#define BM 64
#define BK 32
#define KCH (DDIM / BK)        // 8 k-chunks
#define CHUNK_USH (KC * BK)    // 16384 ushorts = 32 KB per chunk

typedef __attribute__((ext_vector_type(8))) short bf16x8;
typedef __attribute__((ext_vector_type(4))) float f32x4;

__device__ __forceinline__ unsigned short f2bf(float f) {   // RNE f32->bf16
    union { float f; unsigned int u; } a; a.f = f;
    unsigned int r = a.u + 0x7fffu + ((a.u >> 16) & 1u);
    return (unsigned short)(r >> 16);
}
__device__ __forceinline__ float bf2f(unsigned short h) {
    union { unsigned int u; float f; } a; a.u = ((unsigned int)h) << 16;
    return a.f;
}

// ---- prep: c -> chunk-major, LDS-swizzle-baked bf16 hi/lo + csq10 ----
// octet (row n, q) stored at chunk offset (n*4 + (q ^ ((n>>1)&3)))*8 ushorts
__global__ __launch_bounds__(64) void prep_c(const float* __restrict__ c,
                                             unsigned short* __restrict__ bhi,
                                             unsigned short* __restrict__ blo,
                                             float* __restrict__ csq10) {
    const int n = blockIdx.x, lane = threadIdx.x;
    const int d0 = lane * 4;
    float4 v = ((const float4*)(c + (size_t)n * DDIM))[lane];
    float vv[4] = {v.x, v.y, v.z, v.w};
    unsigned short hh[4], ll[4];
    float ssq = 0.f;
    #pragma unroll
    for (int i = 0; i < 4; ++i) {
        ssq += vv[i] * vv[i];
        hh[i] = f2bf(vv[i]);
        ll[i] = f2bf(vv[i] - bf2f(hh[i]));
    }
    #pragma unroll
    for (int off = 32; off; off >>= 1) ssq += __shfl_xor(ssq, off);
    if (lane == 0) csq10[n] = 10.f * ssq;
    const int ks = d0 >> 5;
    const int q  = (d0 >> 3) & 3;
    const int s  = q ^ ((n >> 1) & 3);
    const size_t dst = (size_t)ks * CHUNK_USH + (n * 4 + s) * 8 + (d0 & 7);
    *(ushort4*)(bhi + dst) = make_ushort4(hh[0], hh[1], hh[2], hh[3]);
    *(ushort4*)(blo + dst) = make_ushort4(ll[0], ll[1], ll[2], ll[3]);
}

// ---- main: 512 blocks x 512 threads (8 waves = 4 M-groups x 2 N-groups) ----
union SmemU {
    struct {
        unsigned short Ahi[BM * BK];   // 4 KB
        unsigned short Alo[BM * BK];   // 4 KB
        unsigned short Bhi[KC * BK];   // 32 KB
        unsigned short Blo[KC * BK];   // 32 KB
    } k;
    float lbuf[32 * 516];              // 64.5 KB (pad 516 -> 2-way banks, free)
};

__global__ __launch_bounds__(512, 4) void kmeans_mfma(
    const float* __restrict__ x, const unsigned short* __restrict__ bhi,
    const unsigned short* __restrict__ blo, const float* __restrict__ csq10,
    float* __restrict__ out) {
    __shared__ __align__(16) SmemU sm;
    __shared__ float red[2][2][BM];
    __shared__ float invS[BM];

    const int tid  = threadIdx.x;
    const int w    = tid >> 6, lane = tid & 63;
    const int wm   = w >> 1, wn = w & 1;
    const int cc   = lane & 15, q = lane >> 4;
    const int row0 = blockIdx.x * BM;

    f32x4 acc[16];
    #pragma unroll
    for (int t = 0; t < 16; ++t) acc[t] = (f32x4){0.f, 0.f, 0.f, 0.f};

    // A staging: thread -> (row xr, 4 k's at xc)
    const int    xr   = tid >> 3;
    const int    xc   = (tid & 7) << 2;
    const float* xptr = x + (size_t)(row0 + xr) * DDIM + xc;
    const int    sAw  = (xc >> 3) ^ ((xr >> 1) & 3);
    unsigned short* aHiW = &sm.k.Ahi[xr * BK + sAw * 8 + (xc & 4)];
    unsigned short* aLoW = &sm.k.Alo[xr * BK + sAw * 8 + (xc & 4)];

    // fragment read pointers
    const int             sF   = q ^ ((cc >> 1) & 3);
    const unsigned short* aHiR = &sm.k.Ahi[(wm * 16 + cc) * BK + sF * 8];
    const unsigned short* aLoR = &sm.k.Alo[(wm * 16 + cc) * BK + sF * 8];
    const int             bbase = wn * 256 + cc;

    float4 xv = *(const float4*)xptr;

    for (int ks = 0; ks < KCH; ++ks) {
        // B staging via VGPRs: 8 coalesced uint4 loads batch-issued here,
        // consumed after the barrier -> naturally 8-deep outstanding.
        const unsigned short* hb = bhi + (size_t)ks * CHUNK_USH;
        const unsigned short* lb = blo + (size_t)ks * CHUNK_USH;
        uint4 th[4], tl[4];
        #pragma unroll
        for (int j = 0; j < 4; ++j) {
            const int slot = j * 512 + tid;   // 16B slots, fully coalesced
            th[j] = *(const uint4*)(hb + slot * 8);
            tl[j] = *(const uint4*)(lb + slot * 8);
        }
        __syncthreads();   // previous compute done, safe to overwrite LDS
        #pragma unroll
        for (int j = 0; j < 4; ++j) {
            const int slot = j * 512 + tid;
            *(uint4*)&sm.k.Bhi[slot * 8] = th[j];
            *(uint4*)&sm.k.Blo[slot * 8] = tl[j];
        }
        // A staging: f32 -> hi/lo bf16, swizzled ushort4 write
        {
            float          vv[4] = {xv.x, xv.y, xv.z, xv.w};
            unsigned short hh[4], ll[4];
            #pragma unroll
            for (int i = 0; i < 4; ++i) {
                hh[i] = f2bf(vv[i]);
                ll[i] = f2bf(vv[i] - bf2f(hh[i]));
            }
            *(ushort4*)aHiW = make_ushort4(hh[0], hh[1], hh[2], hh[3]);
            *(ushort4*)aLoW = make_ushort4(ll[0], ll[1], ll[2], ll[3]);
        }
        if (ks < KCH - 1) xv = *(const float4*)(xptr + (ks + 1) * BK);
        __syncthreads();   // staging visible

        bf16x8 ah = *(const bf16x8*)aHiR;
        bf16x8 al = *(const bf16x8*)aLoR;
        #pragma unroll
        for (int t = 0; t < 16; ++t) {
            bf16x8 b = *(const bf16x8*)&sm.k.Bhi[(bbase + t * 16) * BK + sF * 8];
            acc[t]   = __builtin_amdgcn_mfma_f32_16x16x32_bf16(ah, b, acc[t], 0, 0, 0);
        }
        #pragma unroll
        for (int t = 0; t < 16; ++t) {
            bf16x8 b = *(const bf16x8*)&sm.k.Blo[(bbase + t * 16) * BK + sF * 8];
            acc[t]   = __builtin_amdgcn_mfma_f32_16x16x32_bf16(ah, b, acc[t], 0, 0, 0);
        }
        #pragma unroll
        for (int t = 0; t < 16; ++t) {
            bf16x8 b = *(const bf16x8*)&sm.k.Bhi[(bbase + t * 16) * BK + sF * 8];
            acc[t]   = __builtin_amdgcn_mfma_f32_16x16x32_bf16(al, b, acc[t], 0, 0, 0);
        }
    }

    // ---- softmax stats ----
    float csqv[16];
    #pragma unroll
    for (int t = 0; t < 16; ++t) csqv[t] = csq10[bbase + t * 16];
    const int rbase = wm * 16 + q * 4;
    float     M[4];
    #pragma unroll
    for (int g = 0; g < 4; ++g) {
        float pm = -1e30f;
        #pragma unroll
        for (int t = 0; t < 16; ++t) pm = fmaxf(pm, 20.f * acc[t][g] - csqv[t]);
        #pragma unroll
        for (int off = 1; off < 16; off <<= 1) pm = fmaxf(pm, __shfl_xor(pm, off));
        if (cc == 0) red[0][wn][rbase + g] = pm;
        M[g] = pm;
    }
    __syncthreads();
    #pragma unroll
    for (int g = 0; g < 4; ++g) {
        M[g]     = fmaxf(M[g], red[0][1 - wn][rbase + g]);
        float ps = 0.f;
        #pragma unroll
        for (int t = 0; t < 16; ++t) ps += __expf(20.f * acc[t][g] - csqv[t] - M[g]);
        #pragma unroll
        for (int off = 1; off < 16; off <<= 1) ps += __shfl_xor(ps, off);
        if (cc == 0) red[1][wn][rbase + g] = ps;
    }
    __syncthreads();
    if (tid < BM) invS[tid] = 1.f / (red[1][0][tid] + red[1][1][tid]);
    __syncthreads();

    // ---- transpose epilogue: 2 passes of 32 rows through lbuf, plain stores ----
    #pragma unroll
    for (int p = 0; p < 2; ++p) {
        if ((wm >> 1) == p) {
            const int lr = (wm & 1) * 16 + q * 4;
            #pragma unroll
            for (int g = 0; g < 4; ++g) {
                float mg = M[g];
                #pragma unroll
                for (int t = 0; t < 16; ++t)
                    sm.lbuf[(lr + g) * 516 + wn * 256 + t * 16 + cc] =
                        __expf(20.f * acc[t][g] - csqv[t] - mg);
            }
        }
        __syncthreads();
        #pragma unroll
        for (int j = 0; j < 8; ++j) {
            const int   f    = j * 512 + tid;     // 0..4095 float4 slots
            const int   lrow = f >> 7;            // 0..31
            const int   c4   = f & 127;
            float4      v    = *(const float4*)&sm.lbuf[lrow * 516 + c4 * 4];
            const float inv  = invS[p * 32 + lrow];
            *(float4*)(out + (size_t)(row0 + p * 32 + lrow) * KC + c4 * 4) =
                make_float4(v.x * inv, v.y * inv, v.z * inv, v.w * inv);
        }
        __syncthreads();
    }
}

extern "C" void kernel_launch(void* const* d_in, const int* in_sizes, int n_in,
                              void* d_out, int out_size, void* d_ws, size_t ws_size,
                              hipStream_t stream) {
    const float* x   = (const float*)d_in[0];
    const float* c   = (const float*)d_in[1];
    float*       out = (float*)d_out;

    unsigned short* bhi   = (unsigned short*)d_ws;                 // 256 KB
    unsigned short* blo   = bhi + (size_t)KCH * CHUNK_USH;         // 256 KB
    float*          csq10 = (float*)(blo + (size_t)KCH * CHUNK_USH);  // 2 KB

    prep_c<<<KC, 64, 0, stream>>>(c, bhi, blo, csq10);
    kmeans_mfma<<<NROWS / BM, 512, 0, stream>>>(x, bhi, blo, csq10, out);
}

// Round 8
// 148.526 us; speedup vs baseline: 2.3515x; 2.3515x over previous
//
#include <hip/hip_runtime.h>

// KMeans soft-assignment via bf16 hi/lo split MFMA (3 passes), fused softmax.
// logits = (2*x.c - ||c||^2)/T, T=0.1; ||x||^2 cancels in softmax.
// R8: BM=128 (wave = 16 rows x all 512 cols -> wave-local softmax),
// double-buffered B in LDS, launch_bounds(512,2) to PREVENT the 64-reg cap
// spilling that poisoned R2/R3/R4/R7 (phantom FETCH/WRITE = scratch traffic).
// x: [32768,256] f32, c: [512,256] f32, out: [32768,512] f32
#define NROWS 32768
#define KC 512
#define DDIM 256
#define BM 128
#define BK 32
#define KCH (DDIM / BK)        // 8 k-chunks
#define CHUNK_USH (KC * BK)    // 16384 ushorts = 32 KB per chunk
#define ASTR 40                // A LDS row stride (ushorts): 16B-aligned octets, 2-way banks

typedef __attribute__((ext_vector_type(8))) short bf16x8;
typedef __attribute__((ext_vector_type(4))) float f32x4;

union U8 { unsigned short u[8]; bf16x8 v; };

__device__ __forceinline__ unsigned short f2bf(float f) {   // RNE f32->bf16
    union { float f; unsigned int u; } a; a.f = f;
    unsigned int r = a.u + 0x7fffu + ((a.u >> 16) & 1u);
    return (unsigned short)(r >> 16);
}
__device__ __forceinline__ float bf2f(unsigned short h) {
    union { unsigned int u; float f; } a; a.u = ((unsigned int)h) << 16;
    return a.f;
}

// ---- prep: c -> chunk-major, LDS-swizzle-baked bf16 hi/lo + csq10 ----
// octet (row n, q) stored at chunk offset (n*4 + (q ^ ((n>>1)&3)))*8 ushorts
__global__ __launch_bounds__(64) void prep_c(const float* __restrict__ c,
                                             unsigned short* __restrict__ bhi,
                                             unsigned short* __restrict__ blo,
                                             float* __restrict__ csq10) {
    const int n = blockIdx.x, lane = threadIdx.x;
    const int d0 = lane * 4;
    float4 v = ((const float4*)(c + (size_t)n * DDIM))[lane];
    float vv[4] = {v.x, v.y, v.z, v.w};
    unsigned short hh[4], ll[4];
    float ssq = 0.f;
    #pragma unroll
    for (int i = 0; i < 4; ++i) {
        ssq += vv[i] * vv[i];
        hh[i] = f2bf(vv[i]);
        ll[i] = f2bf(vv[i] - bf2f(hh[i]));
    }
    #pragma unroll
    for (int off = 32; off; off >>= 1) ssq += __shfl_xor(ssq, off);
    if (lane == 0) csq10[n] = 10.f * ssq;
    const int ks = d0 >> 5;
    const int q  = (d0 >> 3) & 3;
    const int s  = q ^ ((n >> 1) & 3);
    const size_t dst = (size_t)ks * CHUNK_USH + (n * 4 + s) * 8 + (d0 & 7);
    *(ushort4*)(bhi + dst) = make_ushort4(hh[0], hh[1], hh[2], hh[3]);
    *(ushort4*)(blo + dst) = make_ushort4(ll[0], ll[1], ll[2], ll[3]);
}

// ---- main: 256 blocks x 512 threads (8 waves; wave w = rows w*16..+15, all 512 cols) ----
union SmemU {
    struct { unsigned short Bhi[2][CHUNK_USH], Blo[2][CHUNK_USH]; } k;  // 128 KB
    float lbuf[32 * 516];                                               // 64.5 KB overlay
};

__global__ __launch_bounds__(512, 2) void kmeans_mfma(
    const float* __restrict__ x, const unsigned short* __restrict__ bhi,
    const unsigned short* __restrict__ blo, const float* __restrict__ csq10,
    float* __restrict__ out) {
    __shared__ __align__(16) SmemU sm;
    __shared__ __align__(16) unsigned short Ahi[BM * ASTR], Alo[BM * ASTR];  // 10 KB each

    const int tid  = threadIdx.x;
    const int w    = tid >> 6, lane = tid & 63;
    const int cc   = lane & 15, q = lane >> 4;
    const int row0 = blockIdx.x * BM;

    f32x4 acc[32];
    #pragma unroll
    for (int t = 0; t < 32; ++t) acc[t] = (f32x4){0.f, 0.f, 0.f, 0.f};

    // A staging: thread -> (row xr, 8 k's at xc8)
    const int    xr   = tid >> 2;
    const int    xc8  = (tid & 3) << 3;
    const float* xg   = x + (size_t)(row0 + xr) * DDIM + xc8;
    unsigned short* aHiW = &Ahi[xr * ASTR + xc8];
    unsigned short* aLoW = &Alo[xr * ASTR + xc8];

    // fragment read offsets
    const int sF    = q ^ ((cc >> 1) & 3);
    const int aoff  = (w * 16 + cc) * ASTR + q * 8;
    const int bB    = (4 * cc + sF) * 8;     // + t*512 per col-tile

    uint4  th[4], tl[4];
    float4 a0, a1;

    // ---- prologue: stage chunk 0 into buf 0 ----
    #pragma unroll
    for (int j = 0; j < 4; ++j) {
        const int slot = j * 512 + tid;
        th[j] = *(const uint4*)(bhi + slot * 8);
        tl[j] = *(const uint4*)(blo + slot * 8);
    }
    a0 = *(const float4*)xg;
    a1 = *(const float4*)(xg + 4);
    #pragma unroll
    for (int j = 0; j < 4; ++j) {
        const int slot = j * 512 + tid;
        *(uint4*)&sm.k.Bhi[0][slot * 8] = th[j];
        *(uint4*)&sm.k.Blo[0][slot * 8] = tl[j];
    }
    {
        float vv[8] = {a0.x, a0.y, a0.z, a0.w, a1.x, a1.y, a1.z, a1.w};
        U8 Hi, Lo;
        #pragma unroll
        for (int i = 0; i < 8; ++i) {
            Hi.u[i] = f2bf(vv[i]);
            Lo.u[i] = f2bf(vv[i] - bf2f(Hi.u[i]));
        }
        *(bf16x8*)aHiW = Hi.v;
        *(bf16x8*)aLoW = Lo.v;
    }
    __syncthreads();

    for (int ks = 0; ks < KCH; ++ks) {
        const int pp = ks & 1;
        // issue prefetch loads for next chunk (in flight across the MFMA phase)
        if (ks < KCH - 1) {
            const unsigned short* hb = bhi + (size_t)(ks + 1) * CHUNK_USH;
            const unsigned short* lb = blo + (size_t)(ks + 1) * CHUNK_USH;
            #pragma unroll
            for (int j = 0; j < 4; ++j) {
                const int slot = j * 512 + tid;
                th[j] = *(const uint4*)(hb + slot * 8);
                tl[j] = *(const uint4*)(lb + slot * 8);
            }
            a0 = *(const float4*)(xg + (ks + 1) * BK);
            a1 = *(const float4*)(xg + (ks + 1) * BK + 4);
        }
        // compute on buffer pp
        bf16x8 ah = *(const bf16x8*)&Ahi[aoff];
        bf16x8 al = *(const bf16x8*)&Alo[aoff];
        #pragma unroll
        for (int t = 0; t < 32; ++t) {
            bf16x8 bh = *(const bf16x8*)&sm.k.Bhi[pp][bB + t * 512];
            bf16x8 bl = *(const bf16x8*)&sm.k.Blo[pp][bB + t * 512];
            acc[t] = __builtin_amdgcn_mfma_f32_16x16x32_bf16(ah, bh, acc[t], 0, 0, 0);
            acc[t] = __builtin_amdgcn_mfma_f32_16x16x32_bf16(ah, bl, acc[t], 0, 0, 0);
            acc[t] = __builtin_amdgcn_mfma_f32_16x16x32_bf16(al, bh, acc[t], 0, 0, 0);
        }
        __syncthreads();   // all waves done with buf pp / A
        if (ks < KCH - 1) {
            #pragma unroll
            for (int j = 0; j < 4; ++j) {
                const int slot = j * 512 + tid;
                *(uint4*)&sm.k.Bhi[1 - pp][slot * 8] = th[j];
                *(uint4*)&sm.k.Blo[1 - pp][slot * 8] = tl[j];
            }
            float vv[8] = {a0.x, a0.y, a0.z, a0.w, a1.x, a1.y, a1.z, a1.w};
            U8 Hi, Lo;
            #pragma unroll
            for (int i = 0; i < 8; ++i) {
                Hi.u[i] = f2bf(vv[i]);
                Lo.u[i] = f2bf(vv[i] - bf2f(Hi.u[i]));
            }
            *(bf16x8*)aHiW = Hi.v;
            *(bf16x8*)aLoW = Lo.v;
        }
        __syncthreads();   // staged data visible
    }

    // ---- wave-local softmax (wave owns full rows) ----
    float csqv[32];
    #pragma unroll
    for (int t = 0; t < 32; ++t) csqv[t] = csq10[t * 16 + cc];
    float M[4], I[4];
    #pragma unroll
    for (int g = 0; g < 4; ++g) {
        float pm = -1e30f;
        #pragma unroll
        for (int t = 0; t < 32; ++t) pm = fmaxf(pm, 20.f * acc[t][g] - csqv[t]);
        #pragma unroll
        for (int off = 1; off < 16; off <<= 1) pm = fmaxf(pm, __shfl_xor(pm, off));
        M[g] = pm;
        float ps = 0.f;
        #pragma unroll
        for (int t = 0; t < 32; ++t) ps += __expf(20.f * acc[t][g] - csqv[t] - pm);
        #pragma unroll
        for (int off = 1; off < 16; off <<= 1) ps += __shfl_xor(ps, off);
        I[g] = 1.f / ps;
    }

    // ---- transpose epilogue: 4 passes of 32 rows through lbuf, dense stores ----
    #pragma unroll
    for (int p = 0; p < 4; ++p) {
        if ((w >> 1) == p) {
            const int lr = (w & 1) * 16 + q * 4;
            #pragma unroll
            for (int g = 0; g < 4; ++g) {
                const float mg = M[g], ig = I[g];
                #pragma unroll
                for (int t = 0; t < 32; ++t)
                    sm.lbuf[(lr + g) * 516 + t * 16 + cc] =
                        __expf(20.f * acc[t][g] - csqv[t] - mg) * ig;
            }
        }
        __syncthreads();
        #pragma unroll
        for (int j = 0; j < 8; ++j) {
            const int f    = j * 512 + tid;     // 0..4095 float4 slots
            const int lrow = f >> 7;            // 0..31
            const int c4   = f & 127;
            float4    v    = *(const float4*)&sm.lbuf[lrow * 516 + c4 * 4];
            *(float4*)(out + (size_t)(row0 + p * 32 + lrow) * KC + c4 * 4) = v;
        }
        __syncthreads();
    }
}

extern "C" void kernel_launch(void* const* d_in, const int* in_sizes, int n_in,
                              void* d_out, int out_size, void* d_ws, size_t ws_size,
                              hipStream_t stream) {
    const float* x   = (const float*)d_in[0];
    const float* c   = (const float*)d_in[1];
    float*       out = (float*)d_out;

    unsigned short* bhi   = (unsigned short*)d_ws;                 // 256 KB
    unsigned short* blo   = bhi + (size_t)KCH * CHUNK_USH;         // 256 KB
    float*          csq10 = (float*)(blo + (size_t)KCH * CHUNK_USH);  // 2 KB

    prep_c<<<KC, 64, 0, stream>>>(c, bhi, blo, csq10);
    kmeans_mfma<<<NROWS / BM, 512, 0, stream>>>(x, bhi, blo, csq10, out);
}